// Round 1
// baseline (596.585 us; speedup 1.0000x reference)
//
#include <hip/hip_runtime.h>

// 1D Euler, Roe flux + Harten entropy fix, 32 first-order Euler steps.
// Design:
//  - State stored as PRIMITIVES (rho, u, p) in two ping-pong buffers:
//    even states live in d_out (so state_32 lands exactly in output layout),
//    odd states in d_ws.
//  - Each step kernel: (a) reduces NBLK per-block partial maxima of |u|+c
//    (written by the previous kernel) redundantly per block -> dt,
//    (b) stages tile+halo primitives in LDS, (c) computes each interface
//    flux ONCE into LDS, (d) updates conservatives, converts back to
//    primitives, writes them, and (e) emits this block's partial max of
//    |u'|+c'  for the NEXT step. t accumulates via a ping-pong scalar.
//  - gamma-1 written as 0.4f literal to match np.float32(0.4) exactly.

#define NXC   1048576
#define BLK   256
#define TILE  1024
#define NBLK  (NXC / TILE)   // 1024
#define GAM   1.4f
#define GM1   0.4f
#define CFLC  0.5f
#define DXC   1e-3f
#define EFIX  0.1f
#define NSTEPS 32

__device__ __forceinline__ void roe_flux(float rL, float uL, float pL,
                                         float rR, float uR, float pR,
                                         float& Fr, float& Fm, float& Fe) {
    float EL = pL / GM1 + 0.5f * rL * uL * uL;
    float ER = pR / GM1 + 0.5f * rR * uR * uR;
    float HL = (EL + pL) / rL;
    float HR = (ER + pR) / rR;
    float sL = sqrtf(rL);
    float sR = sqrtf(rR);
    float den = sL + sR;
    float ur = (sL * uL + sR * uR) / den;
    float Hr = (sL * HL + sR * HR) / den;
    float c  = sqrtf(fmaxf(GM1 * (Hr - 0.5f * ur * ur), 1e-10f));
    float eps = EFIX * c;
    float l1 = ur - c;
    float l3 = ur + c;
    float a1 = sqrtf(l1 * l1 + eps * eps);
    float a2 = sqrtf(ur * ur + eps * eps);
    float a3 = sqrtf(l3 * l3 + eps * eps);
    float drho = rR - rL;
    float du   = uR - uL;
    float dp   = pR - pL;
    float c2 = c * c;
    float al2 = drho - dp / c2;
    float al1 = (dp - c * rR * du) / (2.f * c2);
    float al3 = (dp + c * rR * du) / (2.f * c2);
    float FrL = rL * uL, FmL = rL * uL * uL + pL, FeL = uL * (EL + pL);
    float FrR = rR * uR, FmR = rR * uR * uR + pR, FeR = uR * (ER + pR);
    float dr = a1 * al1 + a2 * al2 + a3 * al3;
    float dm = a1 * al1 * l1 + a2 * al2 * ur + a3 * al3 * l3;
    float de = a1 * al1 * (Hr - ur * c) + a2 * al2 * 0.5f * ur * ur
             + a3 * al3 * (Hr + ur * c);
    Fr = 0.5f * (FrL + FrR - dr);
    Fm = 0.5f * (FmL + FmR - dm);
    Fe = 0.5f * (FeL + FeR - de);
}

__device__ __forceinline__ float wave_max(float v) {
    #pragma unroll
    for (int k = 32; k >= 1; k >>= 1)
        v = fmaxf(v, __shfl_xor(v, k));
    return v;
}

// Copy inputs into state_0 (= d_out) as primitives; emit per-block max of
// |u|+c into partials slot 0; zero t.
__global__ __launch_bounds__(BLK) void init_kernel(
        const float* __restrict__ rho, const float* __restrict__ u,
        const float* __restrict__ p, float* __restrict__ st,
        float* __restrict__ pout, float* __restrict__ tbuf) {
    const int tid = threadIdx.x;
    const int base = blockIdx.x * TILE;
    float lm = 0.f;
    for (int j = tid; j < TILE; j += BLK) {
        int g = base + j;
        float r_ = rho[g], u_ = u[g], p_ = p[g];
        st[g] = r_;
        st[NXC + g] = u_;
        st[2 * NXC + g] = p_;
        float c = sqrtf(GAM * p_ / r_);
        lm = fmaxf(lm, fabsf(u_) + c);
    }
    lm = wave_max(lm);
    __shared__ float red[BLK / 64];
    if ((tid & 63) == 0) red[tid >> 6] = lm;
    __syncthreads();
    if (tid == 0) {
        pout[blockIdx.x] = fmaxf(fmaxf(red[0], red[1]), fmaxf(red[2], red[3]));
        if (blockIdx.x == 0) tbuf[0] = 0.f;
    }
}

__global__ __launch_bounds__(BLK) void step_kernel(
        const float* __restrict__ src, float* __restrict__ dst,
        const float* __restrict__ pin, float* __restrict__ pout,
        const float* __restrict__ t_in, float* __restrict__ t_out,
        const float* __restrict__ tf) {
    __shared__ float r[TILE + 2], uu[TILE + 2], pp[TILE + 2];
    __shared__ float Fr[TILE + 1], Fm[TILE + 1], Fe[TILE + 1];
    __shared__ float red[BLK / 64];
    const int tid = threadIdx.x;
    const int base = blockIdx.x * TILE;

    // --- partial-max read (for dt) ---
    float m = 0.f;
    #pragma unroll
    for (int i = tid; i < NBLK; i += BLK) m = fmaxf(m, pin[i]);

    // --- stage tile + halo primitives into LDS (replicated edge ghosts) ---
    for (int i = tid; i < TILE + 2; i += BLK) {
        int g = base - 1 + i;
        g = max(0, min(NXC - 1, g));
        r[i]  = src[g];
        uu[i] = src[NXC + g];
        pp[i] = src[2 * NXC + g];
    }

    m = wave_max(m);
    if ((tid & 63) == 0) red[tid >> 6] = m;
    __syncthreads();   // covers both red[] and the LDS state stage

    float amax = fmaxf(fmaxf(red[0], red[1]), fmaxf(red[2], red[3]));
    float t0 = *t_in;
    float dt = (CFLC * DXC) / amax;
    float rem = fmaxf(*tf - t0, 0.f);
    dt = fminf(dt, rem);
    if (blockIdx.x == 0 && tid == 0) *t_out = t0 + dt;
    float dtdx = dt / DXC;

    // --- one flux per interface (TILE+1 of them) ---
    for (int i = tid; i < TILE + 1; i += BLK) {
        roe_flux(r[i], uu[i], pp[i], r[i + 1], uu[i + 1], pp[i + 1],
                 Fr[i], Fm[i], Fe[i]);
    }
    __syncthreads();

    // --- conservative update, back to primitives, next-step partial max ---
    float lm = 0.f;
    for (int j = tid; j < TILE; j += BLK) {
        float rho = r[j + 1], u = uu[j + 1], p = pp[j + 1];
        float E    = p / GM1 + 0.5f * rho * u * u;
        float rhou = rho * u;
        float rho2  = rho  - dtdx * (Fr[j + 1] - Fr[j]);
        float rhou2 = rhou - dtdx * (Fm[j + 1] - Fm[j]);
        float E2    = E    - dtdx * (Fe[j + 1] - Fe[j]);
        float u2 = rhou2 / rho2;
        float p2 = GM1 * (E2 - 0.5f * rho2 * u2 * u2);
        int g = base + j;
        dst[g] = rho2;
        dst[NXC + g] = u2;
        dst[2 * NXC + g] = p2;
        float c2 = sqrtf(GAM * p2 / rho2);
        lm = fmaxf(lm, fabsf(u2) + c2);
    }
    lm = wave_max(lm);
    __syncthreads();               // red[] reads above are done; safe to reuse
    if ((tid & 63) == 0) red[tid >> 6] = lm;
    __syncthreads();
    if (tid == 0)
        pout[blockIdx.x] = fmaxf(fmaxf(red[0], red[1]), fmaxf(red[2], red[3]));
}

extern "C" void kernel_launch(void* const* d_in, const int* in_sizes, int n_in,
                              void* d_out, int out_size, void* d_ws, size_t ws_size,
                              hipStream_t stream) {
    const float* rho0 = (const float*)d_in[0];
    const float* u0   = (const float*)d_in[1];
    const float* p0   = (const float*)d_in[2];
    const float* tf   = (const float*)d_in[3];
    // d_in[4] = n_steps (always 32 for this problem)

    float* out = (float*)d_out;                 // state buffer for EVEN states
    float* P1  = (float*)d_ws;                  // state buffer for ODD states (3*NX floats)
    float* part = P1 + (size_t)3 * NXC;         // 2 * NBLK partial maxima
    float* tbuf = part + 2 * NBLK;              // 2 floats (ping-pong t)

    init_kernel<<<NBLK, BLK, 0, stream>>>(rho0, u0, p0, out, part, tbuf);

    float* src = out;
    float* dst = P1;
    for (int k = 0; k < NSTEPS; ++k) {
        step_kernel<<<NBLK, BLK, 0, stream>>>(
            src, dst,
            part + (size_t)(k & 1) * NBLK, part + (size_t)((k + 1) & 1) * NBLK,
            tbuf + (k & 1), tbuf + ((k + 1) & 1), tf);
        float* t = src; src = dst; dst = t;
    }
    // NSTEPS even -> state_32 ends in d_out as [rho | u | p]. Done.
}